// Round 4
// baseline (318.595 us; speedup 1.0000x reference)
//
#include <hip/hip_runtime.h>

// image2patch: out[b, i*126+j, r*6+c] = x[b, 0, 2*i + r, 2*j + c]
// IMAGE_SIZE=256, PSIZE=6, STRIDE=2, NPOS=126, BATCH=128, fp32.
//
// R1: coalesced stores + LDS staging.
// R2: issue-path fixes (invariant geometry, LDSW=267, XCD swizzle) -> null.
// R3: persistent 9-tile pipeline (read-latency hiding) -> null.
// R4: register-gather burst + nontemporal stores -> null.
//     => kernel pinned at ~120-125us (2.4x write roofline) across 5 structurally
//        distinct schedules; CU-side counters clean. Unidentified invariant.
// R5 (this round): the ONE never-varied axis — workgroup geometry. All prior
//     kernels: 256-thr blocks, one 18KB band, read-phase|barrier|write-phase,
//     8 blocks/CU. If the floor is workgroup-granularity scheduling (CP launch/
//     drain, per-block phase convoy — invisible to SQ counters, untouched by
//     intra-block pipelining), only block shape moves it. Now: 512-thr blocks,
//     TWO i-bands per block (8 rows staged once: bands share 4/6 rows, reads
//     x1.5 down; 36KB stored per block; 1 barrier per 2 bands; grid 8064;
//     4 blocks/CU). Staging = exactly 1 float4/thread. Emit = proven R4
//     register-burst per 256-thread half.

#define IMG 256
#define PSZ 6
#define NPOS 126
#define BATCHN 128
#define LDSW 267                 // 267 % 32 = 11: mixed-parity bank spread, max ~3-way
#define IPB 2                    // i-bands per block
#define NIB (NPOS / IPB)         // 63 blocks per batch
#define NBLK (BATCHN * NIB)      // 8064
#define NXCD 8

typedef float f32x4 __attribute__((ext_vector_type(4)));

__global__ __launch_bounds__(512) void image2patch_kernel(
    const float* __restrict__ x, float* __restrict__ out) {
  __shared__ float tile[8 * LDSW];           // 8 rows: 2*i0 .. 2*i0+7

  // XCD-chunked bijective swizzle (8064 = 8 * 1008).
  const int cpx = NBLK / NXCD;               // 1008
  const int raw = blockIdx.x;
  const int blk = (raw % NXCD) * cpx + raw / NXCD;

  const int b  = blk / NIB;
  const int i0 = (blk - b * NIB) * IPB;
  const int t  = threadIdx.x;

  // ---- stage rows 2*i0 .. 2*i0+7: exactly one float4 per thread ----
  // row = t & 7 (consecutive lanes spread rows), col4 = t >> 3.
  {
    const int row  = t & 7;
    const int col4 = t >> 3;
    const float* src = x + (size_t)b * (IMG * IMG) + (size_t)(2 * i0 + row) * IMG;
    float4 v = reinterpret_cast<const float4*>(src)[col4];
    float* d = &tile[row * LDSW + col4 * 4];
    d[0] = v.x; d[1] = v.y; d[2] = v.z; d[3] = v.w;        // LDSW odd -> scalar writes
  }
  __syncthreads();

  // ---- emit: half-block 'band' handles i = i0 + band ----
  // Within a half: q = tl + 252*it => k0 = 4*(tl%9), j = tl/9 + 28*it; LDS
  // addrs advance by 2*28 = 56 per it. Band 'band' reads staged rows
  // rr = 2*band + r (r = 0..5), all in-range 0..7.
  const int band = t >> 8;                   // 0 or 1
  const int tl   = t & 255;
  if (tl < 252) {
    const int tj = tl / 9;
    const int m  = tl - 9 * tj;
    const int k0 = 4 * m;
    const int kA = k0,     rA = kA / PSZ, cA = 2 * tj + (kA - PSZ * rA);
    const int kB = k0 + 1, rB = kB / PSZ, cB = 2 * tj + (kB - PSZ * rB);
    const int kC = k0 + 2, rC = kC / PSZ, cC = 2 * tj + (kC - PSZ * rC);
    const int kD = k0 + 3, rD = kD / PSZ, cD = 2 * tj + (kD - PSZ * rD);
    const int base = 2 * band * LDSW;
    const int a0 = base + rA * LDSW + cA;
    const int a1 = base + rB * LDSW + cB;
    const int a2 = base + rC * LDSW + cC;
    const int a3 = base + rD * LDSW + cD;

    // 16-20 independent ds_read_b32, one wait, then pure store burst.
    f32x4 g0, g1, g2, g3, g4;
    g0.x = tile[a0      ]; g0.y = tile[a1      ]; g0.z = tile[a2      ]; g0.w = tile[a3      ];
    g1.x = tile[a0 +  56]; g1.y = tile[a1 +  56]; g1.z = tile[a2 +  56]; g1.w = tile[a3 +  56];
    g2.x = tile[a0 + 112]; g2.y = tile[a1 + 112]; g2.z = tile[a2 + 112]; g2.w = tile[a3 + 112];
    g3.x = tile[a0 + 168]; g3.y = tile[a1 + 168]; g3.z = tile[a2 + 168]; g3.w = tile[a3 + 168];
    if (tl < 126) {
      g4.x = tile[a0 + 224]; g4.y = tile[a1 + 224]; g4.z = tile[a2 + 224]; g4.w = tile[a3 + 224];
    }

    const int i = i0 + band;
    f32x4* outp = reinterpret_cast<f32x4*>(
        out + ((size_t)b * (NPOS * NPOS) + (size_t)i * NPOS) * (PSZ * PSZ));
    __builtin_nontemporal_store(g0, outp + tl);
    __builtin_nontemporal_store(g1, outp + tl + 252);
    __builtin_nontemporal_store(g2, outp + tl + 504);
    __builtin_nontemporal_store(g3, outp + tl + 756);
    if (tl < 126) {
      __builtin_nontemporal_store(g4, outp + tl + 1008);
    }
  }
}

extern "C" void kernel_launch(void* const* d_in, const int* in_sizes, int n_in,
                              void* d_out, int out_size, void* d_ws, size_t ws_size,
                              hipStream_t stream) {
  const float* x = (const float*)d_in[0];
  float* out = (float*)d_out;
  image2patch_kernel<<<NBLK, 512, 0, stream>>>(x, out);
}